// Round 15
// baseline (36.911 us; speedup 1.0000x reference)
//
#include <hip/hip_runtime.h>

#define NB 512          // threads per block (8 waves)
#define APT 16          // atoms per thread (N = NB*APT = 8192)
#define NTYPE 11
#define NATOMS 8192
#define HALF 2048       // dst-range tile -> 24 KB LDS -> 4 blocks/CU (thread-bound)
#define N3 (NATOMS * 3)

// lgkm-only barrier: LDS visibility without draining the global store queue.
#define LDS_BARRIER()  do {                                   \
    asm volatile("s_waitcnt lgkmcnt(0)" ::: "memory");        \
    __builtin_amdgcn_s_barrier();                             \
} while (0)

__global__ __launch_bounds__(NB, 6)   // VGPR cap 85 (measured 40); occupancy is thread-bound at 4 blk/CU
void typed_coords_kernel(const float* __restrict__ coords,
                         const int*   __restrict__ types,
                         const int*   __restrict__ num_atoms,
                         float* __restrict__ out,       // B*3N floats
                         float* __restrict__ out_cnt,   // B*NTYPE floats
                         float* __restrict__ out_off)   // B*NTYPE floats
{
    const int b    = blockIdx.x;
    const int tid  = threadIdx.x;
    const int lane = tid & 63;
    const int wave = tid >> 6;        // 0..7

    __shared__ float    lds_half[HALF * 3];   // 24 KB dst-range tile
    __shared__ unsigned lds_wtot[8][8];       // wave totals (row pad 8)
    __shared__ unsigned lds_pb[8][8];         // per-wave packed bases

    const int na     = num_atoms[b];
    const int base_i = tid * APT;
    float* obase = out + (size_t)b * N3;

    // ---- load my 16 types, pack 4 bits each into 2 uints ----
    unsigned tp0 = 0, tp1 = 0;
    {
        const int* tptr = types + (size_t)b * NATOMS + base_i;
        if (base_i < na) {
            int4 a = reinterpret_cast<const int4*>(tptr)[0];
            int4 c = reinterpret_cast<const int4*>(tptr)[1];
            int4 e4 = reinterpret_cast<const int4*>(tptr)[2];
            int4 g4 = reinterpret_cast<const int4*>(tptr)[3];
            tp0 = (unsigned)a.x | ((unsigned)a.y << 4) | ((unsigned)a.z << 8)  | ((unsigned)a.w << 12)
                | ((unsigned)c.x << 16) | ((unsigned)c.y << 20) | ((unsigned)c.z << 24) | ((unsigned)c.w << 28);
            tp1 = (unsigned)e4.x | ((unsigned)e4.y << 4) | ((unsigned)e4.z << 8)  | ((unsigned)e4.w << 12)
                | ((unsigned)g4.x << 16) | ((unsigned)g4.y << 20) | ((unsigned)g4.z << 24) | ((unsigned)g4.w << 28);
        }
    }
#define TYP(k) ((int)((((k) < 8 ? tp0 : tp1) >> (((k) & 7) * 4)) & 0xFu))

    // ---- per-thread histogram (11 x 5-bit in 2 uints) + per-atom rank (4-bit) ----
    unsigned g0 = 0, g1 = 0, rpk0 = 0, rpk1 = 0;
    if (base_i < na) {
        #pragma unroll
        for (int k = 0; k < APT; ++k) {              // k compile-time
            if (base_i + k < na) {
                int t = TYP(k);
                bool c = t < 6;
                int sh5 = (c ? t : t - 6) * 5;
                unsigned cur  = c ? g0 : g1;
                unsigned rank = (cur >> sh5) & 0xFu; // rank <= 15
                if (k < 8) rpk0 |= rank << (k * 4);
                else       rpk1 |= rank << ((k - 8) * 4);
                unsigned inc = 1u << sh5;
                g0 += c ? inc : 0u;
                g1 += c ? 0u : inc;
            }
        }
    }

    // ---- expand to 6 words of 2x16-bit fields (static indices only) ----
    unsigned x[6], own[6];
    #pragma unroll
    for (int i = 0; i < 6; ++i) x[i] = 0;
    #pragma unroll
    for (int t = 0; t < NTYPE; ++t) {                // t compile-time
        unsigned v = (((t < 6) ? g0 : g1) >> (((t < 6) ? t : t - 6) * 5)) & 31u;
        x[t >> 1] |= v << ((t & 1) * 16);
    }
    #pragma unroll
    for (int i = 0; i < 6; ++i) own[i] = x[i];

    // ---- level-1: in-wave inclusive shfl scan ----
    #pragma unroll
    for (int d = 1; d < 64; d <<= 1) {
        #pragma unroll
        for (int i = 0; i < 6; ++i) {
            unsigned n = __shfl_up(x[i], d);
            if (lane >= d) x[i] += n;
        }
    }
    unsigned e[6];
    #pragma unroll
    for (int i = 0; i < 6; ++i) e[i] = x[i] - own[i];   // exclusive in-wave
    if (lane == 63) {
        #pragma unroll
        for (int i = 0; i < 6; ++i) lds_wtot[wave][i] = x[i];
    }
    LDS_BARRIER();

    // ---- level-2: wave 0 scans the 8 wave totals + type offsets ----
    if (wave == 0 && lane < 8) {
        unsigned y[6], own2[6];
        #pragma unroll
        for (int i = 0; i < 6; ++i) { y[i] = lds_wtot[lane][i]; own2[i] = y[i]; }
        #pragma unroll
        for (int d = 1; d < 8; d <<= 1) {
            #pragma unroll
            for (int i = 0; i < 6; ++i) {
                unsigned n = __shfl_up(y[i], d);
                if (lane >= d) y[i] += n;
            }
        }
        unsigned tot[6], ex2[6], offp[6];
        #pragma unroll
        for (int i = 0; i < 6; ++i) {
            tot[i] = __shfl(y[i], 7);
            ex2[i] = y[i] - own2[i];
            offp[i] = 0;
        }
        unsigned acc = 0;
        #pragma unroll
        for (int t = 0; t < NTYPE; ++t) {            // t compile-time
            unsigned c = (tot[t >> 1] >> ((t & 1) * 16)) & 0xFFFFu;
            offp[t >> 1] |= acc << ((t & 1) * 16);
            if (lane == 0) {
                out_cnt[(size_t)b * NTYPE + t] = (float)c;
                out_off[(size_t)b * NTYPE + t] = (float)acc;
            }
            acc += c;
        }
        #pragma unroll
        for (int i = 0; i < 6; ++i) lds_pb[lane][i] = offp[i] + ex2[i];
    }
    LDS_BARRIER();

    // ---- per-thread packed base: s = pb[wave] + in-wave exclusive ----
    unsigned s[6];
    #pragma unroll
    for (int i = 0; i < 6; ++i) s[i] = lds_pb[wave][i] + e[i];  // broadcast read

    // ---- dst per atom = base16(select) + rank; pack 2x16-bit per reg ----
    unsigned dpk[APT / 2];
    #pragma unroll
    for (int h = 0; h < APT / 2; ++h) dpk[h] = 0xFFFFFFFFu;
    if (base_i < na) {
        #pragma unroll
        for (int k = 0; k < APT; ++k) {              // k compile-time
            if (base_i + k < na) {
                int t = TYP(k);
                int w = t >> 1;                      // nested ternary: static idx
                unsigned u = (w < 2) ? ((w == 0) ? s[0] : s[1])
                           : ((w < 4) ? ((w == 2) ? s[2] : s[3])
                                      : ((w == 4) ? s[4] : s[5]));
                unsigned base16 = (u >> ((t & 1) * 16)) & 0xFFFFu;
                unsigned rank = ((k < 8) ? (rpk0 >> (k * 4))
                                         : (rpk1 >> ((k - 8) * 4))) & 0xFu;
                unsigned d = base16 + rank;
                if (k & 1) dpk[k >> 1] = (dpk[k >> 1] & 0x0000FFFFu) | (d << 16);
                else       dpk[k >> 1] = (dpk[k >> 1] & 0xFFFF0000u) | d;
            }
        }
    }

    // ---- coords -> registers ONCE (short live range, after scan regs die) ----
    float cf[APT * 3];
    {
        const float4* c4 = reinterpret_cast<const float4*>(
            coords + (size_t)b * N3 + (size_t)base_i * 3);      // 192B-aligned
        if (base_i < na) {
            #pragma unroll
            for (int g = 0; g < (APT * 3) / 4; ++g)
                *reinterpret_cast<float4*>(&cf[g * 4]) = c4[g]; // static idx
        } else {
            #pragma unroll
            for (int i = 0; i < APT * 3; ++i) cf[i] = 0.0f;
        }
    }

    // ---- tail-zero stores: [align4(3na), 3N) streams during the passes ----
    {
        int A4 = (3 * na + 3) >> 2;                  // first zero float4
        float4 z = make_float4(0.f, 0.f, 0.f, 0.f);
        float4* o4 = reinterpret_cast<float4*>(obase);
        for (int j = A4 + tid; j < N3 / 4; j += NB) o4[j] = z;
    }

    // ---- pin coords: forbid rematerialized reloads across the pass loop ----
    #pragma unroll
    for (int i = 0; i < APT * 3; ++i) asm volatile("" : "+v"(cf[i]));

    // ---- clipped dst-range passes: only ceil(na/HALF) of them (0..4) ----
    const int npass = (na + HALF - 1) / HALF;        // uniform per block
    #pragma unroll 1
    for (int p = 0; p < npass; ++p) {
        if (p) LDS_BARRIER();                        // prev writeout ds_reads done

        const int n_in = min(HALF, na - p * HALF);   // atoms in this tile (>=1)
        const int nq   = (3 * n_in + 3) >> 2;        // float4s to write

        // zero the 0-3 pad floats at the tile's ragged end
        for (int i = 3 * n_in + tid; i < nq * 4; i += NB) lds_half[i] = 0.0f;

        // scatter my atoms whose dst falls in this range (registers only)
        #pragma unroll
        for (int h = 0; h < APT / 2; ++h) {
            unsigned pk = dpk[h];
            int d0 = (int)(pk & 0xFFFFu) - p * HALF;
            int d1 = (int)(pk >> 16)     - p * HALF;
            if (d0 >= 0 && d0 < HALF) {              // sentinel lands out of range
                lds_half[d0 * 3 + 0] = cf[(h * 2 + 0) * 3 + 0];
                lds_half[d0 * 3 + 1] = cf[(h * 2 + 0) * 3 + 1];
                lds_half[d0 * 3 + 2] = cf[(h * 2 + 0) * 3 + 2];
            }
            if (d1 >= 0 && d1 < HALF) {
                lds_half[d1 * 3 + 0] = cf[(h * 2 + 1) * 3 + 0];
                lds_half[d1 * 3 + 1] = cf[(h * 2 + 1) * 3 + 1];
                lds_half[d1 * 3 + 2] = cf[(h * 2 + 1) * 3 + 2];
            }
        }
        LDS_BARRIER();                               // ds_writes visible

        // coalesced float4 writeout; stores drain without any vmcnt barrier
        float4* o4 = reinterpret_cast<float4*>(obase + (size_t)p * HALF * 3);
        const float4* l4 = reinterpret_cast<const float4*>(lds_half);
        for (int q = tid; q < nq; q += NB) o4[q] = l4[q];
    }
#undef TYP
}

extern "C" void kernel_launch(void* const* d_in, const int* in_sizes, int n_in,
                              void* d_out, int out_size, void* d_ws, size_t ws_size,
                              hipStream_t stream) {
    const float* coords = (const float*)d_in[0];
    const int*   types  = (const int*)d_in[1];
    const int*   nums   = (const int*)d_in[2];
    const int B = in_sizes[2];            // num_atoms has B elements

    float* out     = (float*)d_out;
    float* out_cnt = out + (size_t)B * N3;
    float* out_off = out_cnt + (size_t)B * NTYPE;

    typed_coords_kernel<<<B, NB, 0, stream>>>(coords, types, nums,
                                              out, out_cnt, out_off);
}

// Round 16
// 34.971 us; speedup vs baseline: 1.0555x; 1.0555x over previous
//
#include <hip/hip_runtime.h>

#define NB 1024         // threads per block (16 waves)
#define APT 8           // atoms per thread (N = NB*APT = 8192)
#define NTYPE 11
#define NATOMS 8192
#define HALF 4096       // dst-range tile
#define N3 (NATOMS * 3)

// lgkm-only barrier: LDS visibility without draining the global store queue.
#define LDS_BARRIER()  do {                                   \
    asm volatile("s_waitcnt lgkmcnt(0)" ::: "memory");        \
    __builtin_amdgcn_s_barrier();                             \
} while (0)

__device__ __forceinline__ unsigned pack_types(const int* __restrict__ types,
                                               int b, int base_i, int na)
{
    unsigned tp = 0;
    if (base_i < na) {
        const int* tptr = types + (size_t)b * NATOMS + base_i;
        int4 a = reinterpret_cast<const int4*>(tptr)[0];
        int4 c = reinterpret_cast<const int4*>(tptr)[1];
        tp = (unsigned)a.x | ((unsigned)a.y << 4) | ((unsigned)a.z << 8)  | ((unsigned)a.w << 12)
           | ((unsigned)c.x << 16) | ((unsigned)c.y << 20) | ((unsigned)c.z << 24) | ((unsigned)c.w << 28);
    }
    return tp;
}

__global__ __launch_bounds__(NB, 8)   // 8 waves/EU -> 2 blocks/CU, VGPR<=64
void typed_coords_kernel(const float* __restrict__ coords,
                         const int*   __restrict__ types,
                         const int*   __restrict__ num_atoms,
                         float* __restrict__ out,       // B*3N floats
                         float* __restrict__ out_cnt,   // B*NTYPE floats
                         float* __restrict__ out_off,   // B*NTYPE floats
                         int B)
{
    const int bid  = blockIdx.x;
    const int G    = gridDim.x;       // 512: all blocks co-resident (2/CU)
    const int tid  = threadIdx.x;
    const int lane = tid & 63;
    const int wave = tid >> 6;        // 0..15

    __shared__ float    lds_half[HALF * 3];   // 48 KB dst-range tile
    __shared__ unsigned lds_wtot[16][8];      // wave totals (row pad 8)
    __shared__ unsigned lds_pb[16][8];        // per-wave packed bases

    const int base_i = tid * APT;

    // ---- preload batch-0 state (the only cross-iteration registers) ----
    int      na_cur = num_atoms[bid];
    unsigned tp_cur = pack_types(types, bid, base_i, na_cur);

    #pragma unroll 2
    for (int it = 0; it < 2; ++it) {
        const int b = bid + it * G;
        if (b >= B) break;
        const int na  = na_cur;
        const unsigned tp0 = tp_cur;
        float* obase = out + (size_t)b * N3;

#define TYP(k) ((int)((tp0 >> ((k) * 4)) & 0xFu))

        // ---- per-thread histogram (11 x 5-bit in 2 uints) + per-atom rank ----
        unsigned g0 = 0, g1 = 0, rpk0 = 0;
        if (base_i < na) {
            #pragma unroll
            for (int k = 0; k < APT; ++k) {          // k compile-time
                if (base_i + k < na) {
                    int t = TYP(k);
                    bool c = t < 6;
                    int sh5 = (c ? t : t - 6) * 5;
                    unsigned cur  = c ? g0 : g1;
                    rpk0 |= ((cur >> sh5) & 0xFu) << (k * 4);   // rank <= 7
                    unsigned inc = 1u << sh5;
                    g0 += c ? inc : 0u;
                    g1 += c ? 0u : inc;
                }
            }
        }

        // ---- expand to 6 words of 2x16-bit fields (static indices only) ----
        unsigned x[6], own[6];
        #pragma unroll
        for (int i = 0; i < 6; ++i) x[i] = 0;
        #pragma unroll
        for (int t = 0; t < NTYPE; ++t) {            // t compile-time
            unsigned v = (((t < 6) ? g0 : g1) >> (((t < 6) ? t : t - 6) * 5)) & 31u;
            x[t >> 1] |= v << ((t & 1) * 16);
        }
        #pragma unroll
        for (int i = 0; i < 6; ++i) own[i] = x[i];

        // ---- level-1: in-wave inclusive shfl scan ----
        #pragma unroll
        for (int d = 1; d < 64; d <<= 1) {
            #pragma unroll
            for (int i = 0; i < 6; ++i) {
                unsigned n = __shfl_up(x[i], d);
                if (lane >= d) x[i] += n;
            }
        }
        unsigned e[6];
        #pragma unroll
        for (int i = 0; i < 6; ++i) e[i] = x[i] - own[i];   // exclusive in-wave
        if (lane == 63) {
            #pragma unroll
            for (int i = 0; i < 6; ++i) lds_wtot[wave][i] = x[i];
        }
        LDS_BARRIER();

        // ---- level-2: wave 0 scans the 16 wave totals + type offsets ----
        if (wave == 0 && lane < 16) {
            unsigned y[6], own2[6];
            #pragma unroll
            for (int i = 0; i < 6; ++i) { y[i] = lds_wtot[lane][i]; own2[i] = y[i]; }
            #pragma unroll
            for (int d = 1; d < 16; d <<= 1) {
                #pragma unroll
                for (int i = 0; i < 6; ++i) {
                    unsigned n = __shfl_up(y[i], d);
                    if (lane >= d) y[i] += n;
                }
            }
            unsigned tot[6], ex2[6], offp[6];
            #pragma unroll
            for (int i = 0; i < 6; ++i) {
                tot[i] = __shfl(y[i], 15);
                ex2[i] = y[i] - own2[i];
                offp[i] = 0;
            }
            unsigned acc = 0;
            #pragma unroll
            for (int t = 0; t < NTYPE; ++t) {        // t compile-time
                unsigned c = (tot[t >> 1] >> ((t & 1) * 16)) & 0xFFFFu;
                offp[t >> 1] |= acc << ((t & 1) * 16);
                if (lane == 0) {
                    out_cnt[(size_t)b * NTYPE + t] = (float)c;
                    out_off[(size_t)b * NTYPE + t] = (float)acc;
                }
                acc += c;
            }
            #pragma unroll
            for (int i = 0; i < 6; ++i) lds_pb[lane][i] = offp[i] + ex2[i];
        }
        LDS_BARRIER();

        // ---- per-thread packed base: s = pb[wave] + in-wave exclusive ----
        unsigned s[6];
        #pragma unroll
        for (int i = 0; i < 6; ++i) s[i] = lds_pb[wave][i] + e[i];

        // ---- dst per atom = base16(select) + rank; pack 2x16-bit per reg ----
        unsigned dpk[APT / 2];
        #pragma unroll
        for (int h = 0; h < APT / 2; ++h) dpk[h] = 0xFFFFFFFFu;
        if (base_i < na) {
            #pragma unroll
            for (int k = 0; k < APT; ++k) {          // k compile-time
                if (base_i + k < na) {
                    int t = TYP(k);
                    int w = t >> 1;                  // nested ternary: static idx
                    unsigned u = (w < 2) ? ((w == 0) ? s[0] : s[1])
                               : ((w < 4) ? ((w == 2) ? s[2] : s[3])
                                          : ((w == 4) ? s[4] : s[5]));
                    unsigned base16 = (u >> ((t & 1) * 16)) & 0xFFFFu;
                    unsigned rank = (rpk0 >> (k * 4)) & 0xFu;
                    unsigned d = base16 + rank;
                    if (k & 1) dpk[k >> 1] = (dpk[k >> 1] & 0x0000FFFFu) | (d << 16);
                    else       dpk[k >> 1] = (dpk[k >> 1] & 0xFFFF0000u) | d;
                }
            }
        }

        // ---- coords -> registers ONCE (short live range; round-9 placement) ----
        float cf[APT * 3];
        {
            const float4* c4 = reinterpret_cast<const float4*>(
                coords + (size_t)b * N3 + (size_t)base_i * 3);      // 96B-aligned
            if (base_i < na) {
                #pragma unroll
                for (int g = 0; g < (APT * 3) / 4; ++g)
                    *reinterpret_cast<float4*>(&cf[g * 4]) = c4[g]; // static idx
            } else {
                #pragma unroll
                for (int i = 0; i < APT * 3; ++i) cf[i] = 0.0f;
            }
        }

        // ---- tail-zero stores: [align4(3na), 3N) streams during the passes ----
        {
            int A4 = (3 * na + 3) >> 2;              // first zero float4
            float4 z = make_float4(0.f, 0.f, 0.f, 0.f);
            float4* o4 = reinterpret_cast<float4*>(obase);
            for (int j = A4 + tid; j < N3 / 4; j += NB) o4[j] = z;
        }

        // ---- PREFETCH next batch's types (1+1 regs held; latency hides
        //      under this batch's scatter + writeout) ----
        if (it == 0 && bid + G < B) {
            na_cur = num_atoms[bid + G];
            tp_cur = pack_types(types, bid + G, base_i, na_cur);
        }

        // ---- pin coords: forbid rematerialized reloads across the pass loop ----
        #pragma unroll
        for (int i = 0; i < APT * 3; ++i) asm volatile("" : "+v"(cf[i]));

        // ---- clipped dst-range passes: only ceil(na/HALF) of them ----
        const int npass = (na + HALF - 1) / HALF;    // 0, 1, or 2 (uniform)
        #pragma unroll 1
        for (int p = 0; p < npass; ++p) {
            if (p) LDS_BARRIER();                    // prev writeout ds_reads done

            const int n_in = min(HALF, na - p * HALF);   // atoms in tile (>=1)
            const int nq   = (3 * n_in + 3) >> 2;        // float4s to write

            // zero the 0-3 pad floats at the tile's ragged end
            for (int i = 3 * n_in + tid; i < nq * 4; i += NB) lds_half[i] = 0.0f;

            // scatter my atoms whose dst falls in this range (registers only)
            #pragma unroll
            for (int h = 0; h < APT / 2; ++h) {
                unsigned pk = dpk[h];
                int d0 = (int)(pk & 0xFFFFu) - p * HALF;
                int d1 = (int)(pk >> 16)     - p * HALF;
                if (d0 >= 0 && d0 < HALF) {          // sentinel lands out of range
                    lds_half[d0 * 3 + 0] = cf[(h * 2 + 0) * 3 + 0];
                    lds_half[d0 * 3 + 1] = cf[(h * 2 + 0) * 3 + 1];
                    lds_half[d0 * 3 + 2] = cf[(h * 2 + 0) * 3 + 2];
                }
                if (d1 >= 0 && d1 < HALF) {
                    lds_half[d1 * 3 + 0] = cf[(h * 2 + 1) * 3 + 0];
                    lds_half[d1 * 3 + 1] = cf[(h * 2 + 1) * 3 + 1];
                    lds_half[d1 * 3 + 2] = cf[(h * 2 + 1) * 3 + 2];
                }
            }
            LDS_BARRIER();                           // ds_writes visible

            // coalesced float4 writeout; stores drain without vmcnt barrier,
            // overlapping the next batch's histogram/scan.
            float4* o4 = reinterpret_cast<float4*>(obase + (size_t)p * HALF * 3);
            const float4* l4 = reinterpret_cast<const float4*>(lds_half);
            for (int q = tid; q < nq; q += NB) o4[q] = l4[q];
        }

        // ensure iter-1's lds_wtot writes can't overtake any wave still
        // reading lds_half in this iteration's final writeout
        if (it == 0) LDS_BARRIER();
#undef TYP
    }
}

extern "C" void kernel_launch(void* const* d_in, const int* in_sizes, int n_in,
                              void* d_out, int out_size, void* d_ws, size_t ws_size,
                              hipStream_t stream) {
    const float* coords = (const float*)d_in[0];
    const int*   types  = (const int*)d_in[1];
    const int*   nums   = (const int*)d_in[2];
    const int B = in_sizes[2];            // num_atoms has B elements

    float* out     = (float*)d_out;
    float* out_cnt = out + (size_t)B * N3;
    float* out_off = out_cnt + (size_t)B * NTYPE;

    int grid = (B + 1) / 2;               // 512: all blocks co-resident (2/CU)
    typed_coords_kernel<<<grid, NB, 0, stream>>>(coords, types, nums,
                                                 out, out_cnt, out_off, B);
}

// Round 17
// 31.953 us; speedup vs baseline: 1.1552x; 1.0945x over previous
//
#include <hip/hip_runtime.h>

#define NB 1024         // threads per block (16 waves)
#define APT 8           // atoms per thread (N = NB*APT = 8192)
#define NTYPE 11
#define NATOMS 8192
#define HALF 4096       // dst-range tile
#define N3 (NATOMS * 3)

// lgkm-only barrier: LDS producer/consumer visibility without draining the
// global store queue (vmcnt). No sched_barrier pins (round-10 lesson / m141).
#define LDS_BARRIER()  do {                                   \
    asm volatile("s_waitcnt lgkmcnt(0)" ::: "memory");        \
    __builtin_amdgcn_s_barrier();                             \
} while (0)

__global__ __launch_bounds__(NB, 8)   // 8 waves/EU -> 2 blocks/CU, VGPR<=64
void typed_coords_kernel(const float* __restrict__ coords,
                         const int*   __restrict__ types,
                         const int*   __restrict__ num_atoms,
                         float* __restrict__ out,       // B*3N floats
                         float* __restrict__ out_cnt,   // B*NTYPE floats
                         float* __restrict__ out_off)   // B*NTYPE floats
{
    const int b    = blockIdx.x;
    const int tid  = threadIdx.x;
    const int lane = tid & 63;
    const int wave = tid >> 6;        // 0..15

    __shared__ float    lds_half[HALF * 3];   // 48 KB dst-range tile
    __shared__ unsigned lds_wtot[16][8];      // wave totals (row pad 8)
    __shared__ unsigned lds_pb[16][8];        // per-wave packed bases

    const int na     = num_atoms[b];
    const int base_i = tid * APT;
    float* obase = out + (size_t)b * N3;

    // ---- load my 8 types, pack 4 bits each into 1 uint ----
    unsigned tp0 = 0;
    {
        const int* tptr = types + (size_t)b * NATOMS + base_i;
        if (base_i < na) {
            int4 a = reinterpret_cast<const int4*>(tptr)[0];
            int4 c = reinterpret_cast<const int4*>(tptr)[1];
            tp0 = (unsigned)a.x | ((unsigned)a.y << 4) | ((unsigned)a.z << 8)  | ((unsigned)a.w << 12)
                | ((unsigned)c.x << 16) | ((unsigned)c.y << 20) | ((unsigned)c.z << 24) | ((unsigned)c.w << 28);
        }
    }
#define TYP(k) ((int)((tp0 >> ((k) * 4)) & 0xFu))

    // ---- per-thread histogram (11 x 5-bit in 2 uints) + per-atom rank ----
    unsigned g0 = 0, g1 = 0, rpk0 = 0;
    if (base_i < na) {
        #pragma unroll
        for (int k = 0; k < APT; ++k) {              // k compile-time
            if (base_i + k < na) {
                int t = TYP(k);
                bool c = t < 6;
                int sh5 = (c ? t : t - 6) * 5;
                unsigned cur  = c ? g0 : g1;
                rpk0 |= ((cur >> sh5) & 0xFu) << (k * 4);   // rank <= 7
                unsigned inc = 1u << sh5;
                g0 += c ? inc : 0u;
                g1 += c ? 0u : inc;
            }
        }
    }

    // ---- expand to 6 words of 2x16-bit fields (static indices only) ----
    unsigned x[6], own[6];
    #pragma unroll
    for (int i = 0; i < 6; ++i) x[i] = 0;
    #pragma unroll
    for (int t = 0; t < NTYPE; ++t) {                // t compile-time
        unsigned v = (((t < 6) ? g0 : g1) >> (((t < 6) ? t : t - 6) * 5)) & 31u;
        x[t >> 1] |= v << ((t & 1) * 16);
    }
    #pragma unroll
    for (int i = 0; i < 6; ++i) own[i] = x[i];

    // ---- level-1: in-wave inclusive shfl scan ----
    #pragma unroll
    for (int d = 1; d < 64; d <<= 1) {
        #pragma unroll
        for (int i = 0; i < 6; ++i) {
            unsigned n = __shfl_up(x[i], d);
            if (lane >= d) x[i] += n;
        }
    }
    unsigned e[6];
    #pragma unroll
    for (int i = 0; i < 6; ++i) e[i] = x[i] - own[i];   // exclusive in-wave
    if (lane == 63) {
        #pragma unroll
        for (int i = 0; i < 6; ++i) lds_wtot[wave][i] = x[i];
    }
    LDS_BARRIER();

    // ---- level-2: wave 0 scans the 16 wave totals + type offsets ----
    if (wave == 0 && lane < 16) {
        unsigned y[6], own2[6];
        #pragma unroll
        for (int i = 0; i < 6; ++i) { y[i] = lds_wtot[lane][i]; own2[i] = y[i]; }
        #pragma unroll
        for (int d = 1; d < 16; d <<= 1) {
            #pragma unroll
            for (int i = 0; i < 6; ++i) {
                unsigned n = __shfl_up(y[i], d);
                if (lane >= d) y[i] += n;
            }
        }
        unsigned tot[6], ex2[6], offp[6];
        #pragma unroll
        for (int i = 0; i < 6; ++i) {
            tot[i] = __shfl(y[i], 15);
            ex2[i] = y[i] - own2[i];
            offp[i] = 0;
        }
        unsigned acc = 0;
        #pragma unroll
        for (int t = 0; t < NTYPE; ++t) {            // t compile-time
            unsigned c = (tot[t >> 1] >> ((t & 1) * 16)) & 0xFFFFu;
            offp[t >> 1] |= acc << ((t & 1) * 16);
            if (lane == 0) {
                out_cnt[(size_t)b * NTYPE + t] = (float)c;
                out_off[(size_t)b * NTYPE + t] = (float)acc;
            }
            acc += c;
        }
        #pragma unroll
        for (int i = 0; i < 6; ++i) lds_pb[lane][i] = offp[i] + ex2[i];
    }
    LDS_BARRIER();

    // ---- per-thread packed base: s = pb[wave] + in-wave exclusive ----
    unsigned s[6];
    #pragma unroll
    for (int i = 0; i < 6; ++i) s[i] = lds_pb[wave][i] + e[i];  // broadcast read

    // ---- dst per atom = base16(select) + rank; pack 2x16-bit per reg ----
    unsigned dpk[APT / 2];
    #pragma unroll
    for (int h = 0; h < APT / 2; ++h) dpk[h] = 0xFFFFFFFFu;
    if (base_i < na) {
        #pragma unroll
        for (int k = 0; k < APT; ++k) {              // k compile-time
            if (base_i + k < na) {
                int t = TYP(k);
                int w = t >> 1;                      // nested ternary: static idx
                unsigned u = (w < 2) ? ((w == 0) ? s[0] : s[1])
                           : ((w < 4) ? ((w == 2) ? s[2] : s[3])
                                      : ((w == 4) ? s[4] : s[5]));
                unsigned base16 = (u >> ((t & 1) * 16)) & 0xFFFFu;
                unsigned rank = (rpk0 >> (k * 4)) & 0xFu;
                unsigned d = base16 + rank;
                if (k & 1) dpk[k >> 1] = (dpk[k >> 1] & 0x0000FFFFu) | (d << 16);
                else       dpk[k >> 1] = (dpk[k >> 1] & 0xFFFF0000u) | d;
            }
        }
    }

    // ---- coords -> registers ONCE (short live range; fits 64-VGPR budget) ----
    float cf[APT * 3];
    {
        const float4* c4 = reinterpret_cast<const float4*>(
            coords + (size_t)b * N3 + (size_t)base_i * 3);      // 96B-aligned
        if (base_i < na) {
            #pragma unroll
            for (int g = 0; g < (APT * 3) / 4; ++g)
                *reinterpret_cast<float4*>(&cf[g * 4]) = c4[g]; // static idx
        } else {
            #pragma unroll
            for (int i = 0; i < APT * 3; ++i) cf[i] = 0.0f;
        }
    }

    // ---- early tail-zero stores: [align4(3na), 3N) streams from here on ----
    {
        int A4 = (3 * na + 3) >> 2;                  // first zero float4
        float4 z = make_float4(0.f, 0.f, 0.f, 0.f);
        float4* o4 = reinterpret_cast<float4*>(obase);
        for (int j = A4 + tid; j < N3 / 4; j += NB) o4[j] = z;
    }

    // ---- pin coords: forbid rematerialized reloads across the pass loop ----
    #pragma unroll
    for (int i = 0; i < APT * 3; ++i) asm volatile("" : "+v"(cf[i]));

    // ---- clipped dst-range passes: only ceil(na/HALF) of them ----
    const int npass = (na + HALF - 1) / HALF;        // 0, 1, or 2 (uniform)
    #pragma unroll 1
    for (int p = 0; p < npass; ++p) {
        if (p) LDS_BARRIER();                        // prev writeout ds_reads done

        const int n_in = min(HALF, na - p * HALF);   // atoms in this tile (>=1)
        const int nq   = (3 * n_in + 3) >> 2;        // float4s to write

        // zero the 0-3 pad floats at the tile's ragged end
        for (int i = 3 * n_in + tid; i < nq * 4; i += NB) lds_half[i] = 0.0f;

        // scatter my atoms whose dst falls in this range (registers only)
        #pragma unroll
        for (int h = 0; h < APT / 2; ++h) {
            unsigned pk = dpk[h];
            int d0 = (int)(pk & 0xFFFFu) - p * HALF;
            int d1 = (int)(pk >> 16)     - p * HALF;
            if (d0 >= 0 && d0 < HALF) {              // sentinel lands out of range
                lds_half[d0 * 3 + 0] = cf[(h * 2 + 0) * 3 + 0];
                lds_half[d0 * 3 + 1] = cf[(h * 2 + 0) * 3 + 1];
                lds_half[d0 * 3 + 2] = cf[(h * 2 + 0) * 3 + 2];
            }
            if (d1 >= 0 && d1 < HALF) {
                lds_half[d1 * 3 + 0] = cf[(h * 2 + 1) * 3 + 0];
                lds_half[d1 * 3 + 1] = cf[(h * 2 + 1) * 3 + 1];
                lds_half[d1 * 3 + 2] = cf[(h * 2 + 1) * 3 + 2];
            }
        }
        LDS_BARRIER();                               // ds_writes visible

        // coalesced float4 writeout; stores drain without any vmcnt barrier
        float4* o4 = reinterpret_cast<float4*>(obase + (size_t)p * HALF * 3);
        const float4* l4 = reinterpret_cast<const float4*>(lds_half);
        for (int q = tid; q < nq; q += NB) o4[q] = l4[q];
    }
#undef TYP
}

extern "C" void kernel_launch(void* const* d_in, const int* in_sizes, int n_in,
                              void* d_out, int out_size, void* d_ws, size_t ws_size,
                              hipStream_t stream) {
    const float* coords = (const float*)d_in[0];
    const int*   types  = (const int*)d_in[1];
    const int*   nums   = (const int*)d_in[2];
    const int B = in_sizes[2];            // num_atoms has B elements

    float* out     = (float*)d_out;
    float* out_cnt = out + (size_t)B * N3;
    float* out_off = out_cnt + (size_t)B * NTYPE;

    typed_coords_kernel<<<B, NB, 0, stream>>>(coords, types, nums,
                                              out, out_cnt, out_off);
}